// Round 2
// baseline (348.772 us; speedup 1.0000x reference)
//
#include <hip/hip_runtime.h>

// B=16, S=8192, D=256, N=64, IDX=3, slot-norm softmax.
// logits = (x·Q' + qb)/16 with Q' = queries@Wk;  out = (wsum·Wv^T)/denom + bv
// wsum[b,:] = sum_s p3[b,s]·x[b,s,:], denom[b] = sum_s p3[b,s].
// v2: mask pre-packed to bitfields (1MB); attn_main has ZERO per-tile barriers,
// A-frags direct from global, Q' frag-ordered in LDS (conflict-free b128 reads),
// wsum via L2-hot re-read of tile rows in C-layout (no cross-lane a_s shuffle).

#define B_ 16
#define S_ 8192
#define D_ 256
#define N_ 64
#define NEG_ (-9e15f)

typedef __attribute__((ext_vector_type(8))) short s8_t;   // 8 bf16 MFMA frag
typedef __attribute__((ext_vector_type(4))) float f4_t;   // 4 fp32 MFMA acc
typedef unsigned int u32;
typedef unsigned short u16;

__device__ __forceinline__ u16 f2bf(float f) {
  u32 u = __builtin_bit_cast(u32, f);
  u += 0x7fffu + ((u >> 16) & 1u);   // RNE
  return (u16)(u >> 16);
}

// ---- pack mask [16,64,8192] i32 -> pm [16,8192] u64 (bit n = mask[b][n][s]!=0) ----
__global__ void pack_mask(const int* __restrict__ mask, uint2* __restrict__ pm) {
  const int b = blockIdx.y;
  const int s = blockIdx.x * 256 + threadIdx.x;
  const int* mp = mask + (long)b * N_ * S_ + s;
  u32 lo = 0, hi = 0;
#pragma unroll 16
  for (int n = 0; n < 32; ++n) lo |= (u32)(mp[n * S_] != 0) << n;
#pragma unroll 16
  for (int n = 0; n < 32; ++n) hi |= (u32)(mp[(32 + n) * S_] != 0) << n;
  uint2 r; r.x = lo; r.y = hi;
  pm[b * S_ + s] = r;
}

// ---- prep: Q' = queries@Wk -> bf16, written FRAG-ORDERED for MFMA B-operand;
//      qb[n] = queries[n]·bk ----
__global__ void prep_qk(const float* __restrict__ queries, const float* __restrict__ Wk,
                        const float* __restrict__ bk, u16* __restrict__ qf,
                        float* __restrict__ qb) {
  __shared__ float ql[D_];
  __shared__ float rb[D_];
  const int n = blockIdx.x, d = threadIdx.x;
  const float qv = queries[n * D_ + d];
  ql[d] = qv;
  rb[d] = qv * bk[d];
  __syncthreads();
  float a0 = 0.f, a1 = 0.f, a2 = 0.f, a3 = 0.f;
#pragma unroll 4
  for (int e = 0; e < D_; e += 4) {   // Wk rows read coalesced over d
    a0 = fmaf(ql[e + 0], Wk[(e + 0) * D_ + d], a0);
    a1 = fmaf(ql[e + 1], Wk[(e + 1) * D_ + d], a1);
    a2 = fmaf(ql[e + 2], Wk[(e + 2) * D_ + d], a2);
    a3 = fmaf(ql[e + 3], Wk[(e + 3) * D_ + d], a3);
  }
  const float acc = (a0 + a1) + (a2 + a3);
  // frag layout: elem j of frag (t4,c,lane=g*16+c15) = Q'[16t4+c15][32c+8g+j]
  const int t4 = n >> 4, c15 = n & 15, c = d >> 5, g = (d >> 3) & 3, j = d & 7;
  qf[((t4 * 8 + c) * 64 + g * 16 + c15) * 8 + j] = f2bf(acc);
  for (int s = 128; s > 0; s >>= 1) { __syncthreads(); if (d < s) rb[d] += rb[d + s]; }
  if (d == 0) qb[n] = rb[0];
}

// ---- main: zero per-tile barriers; one barrier total (Q' staging) ----
__global__ __launch_bounds__(256) void attn_main(
    const float* __restrict__ x, const uint2* __restrict__ pm,
    const u16* __restrict__ qf, const float* __restrict__ qb,
    float* __restrict__ wsum, float* __restrict__ denom, float* __restrict__ att) {
  __shared__ __align__(16) u16 q_lds[N_ * D_];  // 32KB, frag-ordered

  const int t = threadIdx.x;
  const int lane = t & 63;
  const int w = t >> 6;        // wave -> s rows 16w..16w+15
  const int c15 = lane & 15;
  const int g = lane >> 4;
  const int b = blockIdx.y;
  const int sbase = blockIdx.x * 128;  // 64 s-blocks x 2 tiles x 64

  // stage Q' (linear 32KB copy — frag order already matches readers)
#pragma unroll
  for (int i = 0; i < 8; ++i)
    ((uint4*)q_lds)[t + 256 * i] = ((const uint4*)qf)[t + 256 * i];

  float qbv0 = qb[c15], qbv1 = qb[16 + c15], qbv2 = qb[32 + c15], qbv3 = qb[48 + c15];

  float wacc[4][4] = {{0.f,0.f,0.f,0.f},{0.f,0.f,0.f,0.f},{0.f,0.f,0.f,0.f},{0.f,0.f,0.f,0.f}};
  float dacc = 0.f;
  __syncthreads();

  for (int tt = 0; tt < 2; ++tt) {
    const int s0 = sbase + tt * 64;
    // mask bits for this lane's C-rows (issued early; tiny, broadcast-heavy)
    uint2 mm[4];
#pragma unroll
    for (int r = 0; r < 4; ++r) mm[r] = pm[b * S_ + s0 + 16 * w + g * 4 + r];

    // logits: A-frags straight from global (row 16w+c15), B-frags from LDS
    const float* xrow = x + (((long)b * S_) + s0 + 16 * w + c15) * D_ + g * 8;
    f4_t acc0 = {0.f,0.f,0.f,0.f}, acc1 = {0.f,0.f,0.f,0.f};
    f4_t acc2 = {0.f,0.f,0.f,0.f}, acc3 = {0.f,0.f,0.f,0.f};
#pragma unroll
    for (int c = 0; c < 8; ++c) {
      const float4 v0 = *(const float4*)(xrow + c * 32);
      const float4 v1 = *(const float4*)(xrow + c * 32 + 4);
      s8_t a;
      u32* ap = (u32*)&a;
      ap[0] = (u32)f2bf(v0.x) | ((u32)f2bf(v0.y) << 16);
      ap[1] = (u32)f2bf(v0.z) | ((u32)f2bf(v0.w) << 16);
      ap[2] = (u32)f2bf(v1.x) | ((u32)f2bf(v1.y) << 16);
      ap[3] = (u32)f2bf(v1.z) | ((u32)f2bf(v1.w) << 16);
      acc0 = __builtin_amdgcn_mfma_f32_16x16x32_bf16(a, *(const s8_t*)&q_lds[((0 * 8 + c) * 64 + lane) * 8], acc0, 0, 0, 0);
      acc1 = __builtin_amdgcn_mfma_f32_16x16x32_bf16(a, *(const s8_t*)&q_lds[((1 * 8 + c) * 64 + lane) * 8], acc1, 0, 0, 0);
      acc2 = __builtin_amdgcn_mfma_f32_16x16x32_bf16(a, *(const s8_t*)&q_lds[((2 * 8 + c) * 64 + lane) * 8], acc2, 0, 0, 0);
      acc3 = __builtin_amdgcn_mfma_f32_16x16x32_bf16(a, *(const s8_t*)&q_lds[((3 * 8 + c) * 64 + lane) * 8], acc3, 0, 0, 0);
    }

    // softmax over n=64; C-layout: col=c15 (n within t4), row=g*4+r
    float unorm[4];
#pragma unroll
    for (int r = 0; r < 4; ++r) {
      const float lf0 = ((mm[r].x >> c15) & 1)        ? (acc0[r] + qbv0) * 0.0625f : NEG_;
      const float lf1 = ((mm[r].x >> (16 + c15)) & 1) ? (acc1[r] + qbv1) * 0.0625f : NEG_;
      const float lf2 = ((mm[r].y >> c15) & 1)        ? (acc2[r] + qbv2) * 0.0625f : NEG_;
      const float lf3 = ((mm[r].y >> (16 + c15)) & 1) ? (acc3[r] + qbv3) * 0.0625f : NEG_;
      float m = fmaxf(fmaxf(lf0, lf1), fmaxf(lf2, lf3));
      m = fmaxf(m, __shfl_xor(m, 1));
      m = fmaxf(m, __shfl_xor(m, 2));
      m = fmaxf(m, __shfl_xor(m, 4));
      m = fmaxf(m, __shfl_xor(m, 8));
      const float e0 = __expf(lf0 - m);
      float sm = e0 + __expf(lf1 - m) + __expf(lf2 - m) + __expf(lf3 - m);
      sm += __shfl_xor(sm, 1);
      sm += __shfl_xor(sm, 2);
      sm += __shfl_xor(sm, 4);
      sm += __shfl_xor(sm, 8);
      const float e3 = __shfl(e0, (lane & 48) | 3);  // n=IDX=3: t4=0, c15==3
      unorm[r] = e3 / sm;
    }
    if (c15 == 3) {
      f4_t u = {unorm[0], unorm[1], unorm[2], unorm[3]};
      *(f4_t*)&att[(long)b * S_ + s0 + 16 * w + g * 4] = u;
    }

    // wsum: rows g*4+r (unorm local!), cols c15*16..+15, L2-hot re-read fp32
    const float* wrow = x + (((long)b * S_) + s0 + 16 * w + g * 4) * D_ + c15 * 16;
#pragma unroll
    for (int r = 0; r < 4; ++r) {
      const float a_s = unorm[r];
#pragma unroll
      for (int k = 0; k < 4; ++k) {
        const float4 v = *(const float4*)(wrow + r * D_ + k * 4);
        wacc[k][0] = fmaf(a_s, v.x, wacc[k][0]);
        wacc[k][1] = fmaf(a_s, v.y, wacc[k][1]);
        wacc[k][2] = fmaf(a_s, v.z, wacc[k][2]);
        wacc[k][3] = fmaf(a_s, v.w, wacc[k][3]);
      }
      dacc += a_s;
    }
  }

  // reduce over g (lane bits 4,5): rows of the whole wave
#pragma unroll
  for (int k = 0; k < 4; ++k)
#pragma unroll
    for (int j = 0; j < 4; ++j) {
      wacc[k][j] += __shfl_xor(wacc[k][j], 16);
      wacc[k][j] += __shfl_xor(wacc[k][j], 32);
    }
  dacc += __shfl_xor(dacc, 16);
  dacc += __shfl_xor(dacc, 32);

  // lane (c15,g) commits d = c15*16 + g*4 + j  (select chunk k=g)
#pragma unroll
  for (int j = 0; j < 4; ++j) {
    const float lo = (g & 1) ? wacc[1][j] : wacc[0][j];
    const float hi = (g & 1) ? wacc[3][j] : wacc[2][j];
    const float val = (g & 2) ? hi : lo;
    atomicAdd(&wsum[b * D_ + c15 * 16 + g * 4 + j], val);
  }
  if (lane == 0) atomicAdd(&denom[b], dacc);
}

// ---- finalize: part 0 => out GEMV; parts 1..32 => att renorm ----
__global__ void finalize_k(const float* __restrict__ wsum, const float* __restrict__ denom,
                           const float* __restrict__ Wv, const float* __restrict__ bv,
                           float* __restrict__ out, float* __restrict__ att) {
  const int b = blockIdx.x, t = threadIdx.x, part = blockIdx.y;
  const float dn = denom[b];
  if (part == 0) {
    __shared__ float wl[D_];
    wl[t] = wsum[b * D_ + t];
    __syncthreads();
    const float4* wr = (const float4*)&Wv[t * D_];
    const float4* wv = (const float4*)wl;
    float s0 = 0.f, s1 = 0.f, s2 = 0.f, s3 = 0.f;
#pragma unroll 8
    for (int e = 0; e < 64; ++e) {
      const float4 a = wv[e], w4 = wr[e];
      s0 = fmaf(a.x, w4.x, s0); s1 = fmaf(a.y, w4.y, s1);
      s2 = fmaf(a.z, w4.z, s2); s3 = fmaf(a.w, w4.w, s3);
    }
    out[b * D_ + t] = ((s0 + s1) + (s2 + s3)) / dn + bv[t];
  } else {
    const float inv = 1.0f / dn;
    const int s = (part - 1) * 256 + t;
    att[(long)b * S_ + s] *= inv;
  }
}

extern "C" void kernel_launch(void* const* d_in, const int* in_sizes, int n_in,
                              void* d_out, int out_size, void* d_ws, size_t ws_size,
                              hipStream_t stream) {
  const float* x = (const float*)d_in[0];        // [16,8192,256]
  const int* mask = (const int*)d_in[1];         // [16,64,8192]
  const float* Wv = (const float*)d_in[2];
  const float* bv = (const float*)d_in[3];
  const float* Wk = (const float*)d_in[4];
  const float* bk = (const float*)d_in[5];
  const float* queries = (const float*)d_in[6];  // [64,256]

  char* ws = (char*)d_ws;
  float* wsum = (float*)ws;                  // [0, 16384)
  float* denom = (float*)(ws + 16384);       // [16384, 16448)
  float* qb = (float*)(ws + 16448);          // [16448, 17472)
  u16* qf = (u16*)(ws + 17472);              // [17472, 50240)  32KB frag-ordered Q'
  uint2* pm = (uint2*)(ws + 50240);          // [50240, 50240+1MB) packed mask
  float* out = (float*)d_out;                // 16*256
  float* att = out + B_ * D_;                // 16*8192

  hipMemsetAsync(wsum, 0, 16448, stream);    // wsum + denom
  pack_mask<<<dim3(32, B_), 256, 0, stream>>>(mask, pm);
  prep_qk<<<N_, D_, 0, stream>>>(queries, Wk, bk, qf, qb);
  attn_main<<<dim3(64, B_), 256, 0, stream>>>(x, pm, qf, qb, wsum, denom, att);
  finalize_k<<<dim3(B_, 33), 256, 0, stream>>>(wsum, denom, Wv, bv, out, att);
}

// Round 3
// 323.180 us; speedup vs baseline: 1.0792x; 1.0792x over previous
//
#include <hip/hip_runtime.h>

// B=16, S=8192, D=256, N=64, IDX=3, slot-norm softmax.
// logits = (x·Q' + qb)/16 with Q' = queries@Wk;  out = (wsum·Wv^T)/denom + bv
// wsum[b,:] = sum_s p3[b,s]·x[b,s,:], denom[b] = sum_s p3[b,s].
// v3: coalesced LDS staging (v1) + 4 blocks/CU: Q' B-frags read from L2-resident
// global (wave-contiguous 1KB), mask packed in-kernel, no global atomics
// (per-block partials + finalize reduce). All LDS patterns bank-even.

#define B_ 16
#define S_ 8192
#define D_ 256
#define N_ 64
#define NEG_ (-9e15f)
#define LSTR 264  // LDS row stride in bf16 elems

typedef __attribute__((ext_vector_type(8))) short s8_t;   // 8 bf16 MFMA frag
typedef __attribute__((ext_vector_type(4))) float f4_t;   // 4 fp32 MFMA acc
typedef unsigned int u32;
typedef unsigned short u16;

__device__ __forceinline__ u16 f2bf(float f) {
  u32 u = __builtin_bit_cast(u32, f);
  u += 0x7fffu + ((u >> 16) & 1u);   // RNE
  return (u16)(u >> 16);
}
__device__ __forceinline__ float bflo(u32 p) { return __builtin_bit_cast(float, p << 16); }
__device__ __forceinline__ float bfhi(u32 p) { return __builtin_bit_cast(float, p & 0xffff0000u); }

// ---- prep: Q' = queries@Wk -> bf16 FRAG-ORDERED for MFMA B-operand; qb[n]=q·bk ----
__global__ void prep_qk(const float* __restrict__ queries, const float* __restrict__ Wk,
                        const float* __restrict__ bk, u16* __restrict__ qf,
                        float* __restrict__ qb) {
  __shared__ float ql[D_];
  __shared__ float rb[D_];
  const int n = blockIdx.x, d = threadIdx.x;
  const float qv = queries[n * D_ + d];
  ql[d] = qv;
  rb[d] = qv * bk[d];
  __syncthreads();
  float a0 = 0.f, a1 = 0.f, a2 = 0.f, a3 = 0.f;
#pragma unroll 4
  for (int e = 0; e < D_; e += 4) {
    a0 = fmaf(ql[e + 0], Wk[(e + 0) * D_ + d], a0);
    a1 = fmaf(ql[e + 1], Wk[(e + 1) * D_ + d], a1);
    a2 = fmaf(ql[e + 2], Wk[(e + 2) * D_ + d], a2);
    a3 = fmaf(ql[e + 3], Wk[(e + 3) * D_ + d], a3);
  }
  const float acc = (a0 + a1) + (a2 + a3);
  // frag elem j of frag (t4,c,lane=g*16+c15) = Q'[16t4+c15][32c+8g+j]
  const int t4 = n >> 4, c15 = n & 15, c = d >> 5, g = (d >> 3) & 3, j = d & 7;
  qf[((t4 * 8 + c) * 64 + g * 16 + c15) * 8 + j] = f2bf(acc);
  for (int s = 128; s > 0; s >>= 1) { __syncthreads(); if (d < s) rb[d] += rb[d + s]; }
  if (d == 0) qb[n] = rb[0];
}

// ---- main ----
__global__ __launch_bounds__(256, 4) void attn_main(
    const float* __restrict__ x, const int* __restrict__ mask,
    const u16* __restrict__ qf, const float* __restrict__ qb,
    float* __restrict__ pw, float* __restrict__ dpart, float* __restrict__ att) {
  __shared__ __align__(16) u16 in_lds[64 * LSTR];  // 33792 B x-tile (bf16)
  __shared__ u32 pm[4 * 64];                       // mask bits
  float* ldsW = (float*)in_lds;                    // epilogue overlay (257 floats)

  const int t = threadIdx.x;
  const int lane = t & 63;
  const int w = t >> 6;        // wave -> s rows 16w..16w+15
  const int c15 = lane & 15;
  const int g = lane >> 4;
  const int b = blockIdx.y;
  const int sb = blockIdx.x;
  const int sbase = sb * 128;  // 64 s-blocks x 2 tiles x 64

  const float qbv0 = qb[c15], qbv1 = qb[16 + c15], qbv2 = qb[32 + c15], qbv3 = qb[48 + c15];
  const s8_t* qfs = (const s8_t*)qf;  // frag index (t4*8+c)*64+lane : 1KB/wave, L2-hot

  f4_t wacc = {0.f, 0.f, 0.f, 0.f};  // lane owns cols lane*4..+3
  float dacc = 0.f;

  for (int tt = 0; tt < 2; ++tt) {
    const int s0 = sbase + tt * 64;
    __syncthreads();  // prior-tile readers done before restage
    // stage x tile fp32->bf16: per it, wave reads 1KB contiguous
    {
      const int col = (t & 63) * 4;
#pragma unroll
      for (int it = 0; it < 16; ++it) {
        const int row = it * 4 + w;
        const float4 v = *(const float4*)&x[(((long)b * S_) + s0 + row) * D_ + col];
        uint2 h;
        h.x = (u32)f2bf(v.x) | ((u32)f2bf(v.y) << 16);
        h.y = (u32)f2bf(v.z) | ((u32)f2bf(v.w) << 16);
        *(uint2*)&in_lds[row * LSTR + col] = h;
      }
      // mask bits: wave reads 64 consecutive ints per n-row (coalesced 256B)
      const int s = t & 63, p = t >> 6;
      const int* mrow = mask + ((long)b * N_ + p * 16) * S_ + sbase + tt * 64 + s;
      u32 bits = 0;
#pragma unroll
      for (int i = 0; i < 16; ++i) bits |= (u32)(mrow[i * S_] != 0) << i;
      pm[p * 64 + s] = bits;
    }
    __syncthreads();

    // logits: A-frags from LDS (bank-even b128), B-frags from global L2
    const u16* arow = &in_lds[(16 * w + c15) * LSTR + g * 8];
    f4_t acc0 = {0.f,0.f,0.f,0.f}, acc1 = {0.f,0.f,0.f,0.f};
    f4_t acc2 = {0.f,0.f,0.f,0.f}, acc3 = {0.f,0.f,0.f,0.f};
#pragma unroll
    for (int c = 0; c < 8; ++c) {
      const s8_t a  = *(const s8_t*)&arow[c * 32];
      const s8_t b0 = qfs[(0 * 8 + c) * 64 + lane];
      const s8_t b1 = qfs[(1 * 8 + c) * 64 + lane];
      const s8_t b2 = qfs[(2 * 8 + c) * 64 + lane];
      const s8_t b3 = qfs[(3 * 8 + c) * 64 + lane];
      acc0 = __builtin_amdgcn_mfma_f32_16x16x32_bf16(a, b0, acc0, 0, 0, 0);
      acc1 = __builtin_amdgcn_mfma_f32_16x16x32_bf16(a, b1, acc1, 0, 0, 0);
      acc2 = __builtin_amdgcn_mfma_f32_16x16x32_bf16(a, b2, acc2, 0, 0, 0);
      acc3 = __builtin_amdgcn_mfma_f32_16x16x32_bf16(a, b3, acc3, 0, 0, 0);
    }

    // softmax over n=64; C-layout: col=c15 (n within t4), row=g*4+r
    float unorm[4];
#pragma unroll
    for (int r = 0; r < 4; ++r) {
      const int sl = 16 * w + g * 4 + r;
      const u32 m0 = pm[0 * 64 + sl], m1 = pm[1 * 64 + sl];
      const u32 m2 = pm[2 * 64 + sl], m3 = pm[3 * 64 + sl];
      const float lf0 = ((m0 >> c15) & 1) ? (acc0[r] + qbv0) * 0.0625f : NEG_;
      const float lf1 = ((m1 >> c15) & 1) ? (acc1[r] + qbv1) * 0.0625f : NEG_;
      const float lf2 = ((m2 >> c15) & 1) ? (acc2[r] + qbv2) * 0.0625f : NEG_;
      const float lf3 = ((m3 >> c15) & 1) ? (acc3[r] + qbv3) * 0.0625f : NEG_;
      float m = fmaxf(fmaxf(lf0, lf1), fmaxf(lf2, lf3));
      m = fmaxf(m, __shfl_xor(m, 1));
      m = fmaxf(m, __shfl_xor(m, 2));
      m = fmaxf(m, __shfl_xor(m, 4));
      m = fmaxf(m, __shfl_xor(m, 8));
      const float e0 = __expf(lf0 - m);
      float sm = e0 + __expf(lf1 - m) + __expf(lf2 - m) + __expf(lf3 - m);
      sm += __shfl_xor(sm, 1);
      sm += __shfl_xor(sm, 2);
      sm += __shfl_xor(sm, 4);
      sm += __shfl_xor(sm, 8);
      const float e3 = __shfl(e0, (lane & 48) | 3);  // n=IDX=3: t4=0, c15==3
      unorm[r] = e3 / sm;
    }
    if (c15 == 3) {
      f4_t u = {unorm[0], unorm[1], unorm[2], unorm[3]};
      *(f4_t*)&att[(long)b * S_ + s0 + 16 * w + g * 4] = u;
    }

    // wsum: lane's 4 cols over this wave's 16 rows (bank-even b64 reads)
#pragma unroll
    for (int r = 0; r < 4; ++r) {
#pragma unroll
      for (int gg = 0; gg < 4; ++gg) {
        const float a_s = __shfl(unorm[r], gg * 16);  // row 16w+gg*4+r
        const uint2 h = *(const uint2*)&in_lds[(16 * w + gg * 4 + r) * LSTR + lane * 4];
        wacc[0] = fmaf(a_s, bflo(h.x), wacc[0]);
        wacc[1] = fmaf(a_s, bfhi(h.x), wacc[1]);
        wacc[2] = fmaf(a_s, bflo(h.y), wacc[2]);
        wacc[3] = fmaf(a_s, bfhi(h.y), wacc[3]);
        dacc += a_s;  // lane-uniform: wave's row sum
      }
    }
  }

  // block-combine via LDS (no global atomics)
  __syncthreads();
  if (t < 64) { f4_t z = {0.f,0.f,0.f,0.f}; *(f4_t*)&ldsW[t * 4] = z; }
  if (t == 64) ldsW[D_] = 0.f;
  __syncthreads();
#pragma unroll
  for (int j = 0; j < 4; ++j) atomicAdd(&ldsW[lane * 4 + j], wacc[j]);
  if (lane == 0) atomicAdd(&ldsW[D_], dacc);
  __syncthreads();
  const int blk = b * 64 + sb;
  if (t < D_) pw[(long)blk * D_ + t] = ldsW[t];
  if (t == 0) dpart[blk] = ldsW[D_];
}

// ---- finalize: part 0 => reduce wsum + GEMV; parts 1..32 => att renorm ----
__global__ void finalize_k(const float* __restrict__ pw, const float* __restrict__ dpart,
                           const float* __restrict__ Wv, const float* __restrict__ bv,
                           float* __restrict__ out, float* __restrict__ att) {
  __shared__ float red[64];
  __shared__ float wl[D_];
  const int b = blockIdx.x, t = threadIdx.x, part = blockIdx.y;
  // denom = sum of this b's 64 block partials
  if (t < 64) red[t] = dpart[b * 64 + t];
  __syncthreads();
  if (t < 32) red[t] += red[t + 32];
  __syncthreads();
  if (t < 16) red[t] += red[t + 16];
  __syncthreads();
  if (t < 8) red[t] += red[t + 8];
  __syncthreads();
  if (t < 4) red[t] += red[t + 4];
  __syncthreads();
  if (t < 2) red[t] += red[t + 2];
  __syncthreads();
  if (t == 0) red[0] += red[1];
  __syncthreads();
  const float dn = red[0];
  if (part == 0) {
    float s0 = 0.f, s1 = 0.f, s2 = 0.f, s3 = 0.f;
    const float* p = pw + (long)b * 64 * D_ + t;
#pragma unroll 4
    for (int sb = 0; sb < 64; sb += 4) {  // coalesced 1KB per iter
      s0 += p[(sb + 0) * D_]; s1 += p[(sb + 1) * D_];
      s2 += p[(sb + 2) * D_]; s3 += p[(sb + 3) * D_];
    }
    wl[t] = (s0 + s1) + (s2 + s3);
    __syncthreads();
    const float4* wr = (const float4*)&Wv[t * D_];
    const float4* wv = (const float4*)wl;
    float d0 = 0.f, d1 = 0.f, d2 = 0.f, d3 = 0.f;
#pragma unroll 8
    for (int e = 0; e < 64; ++e) {
      const float4 a = wv[e], w4 = wr[e];
      d0 = fmaf(a.x, w4.x, d0); d1 = fmaf(a.y, w4.y, d1);
      d2 = fmaf(a.z, w4.z, d2); d3 = fmaf(a.w, w4.w, d3);
    }
    out[b * D_ + t] = ((d0 + d1) + (d2 + d3)) / dn + bv[t];
  } else {
    const float inv = 1.0f / dn;
    att[(long)b * S_ + (part - 1) * 256 + t] *= inv;
  }
}

extern "C" void kernel_launch(void* const* d_in, const int* in_sizes, int n_in,
                              void* d_out, int out_size, void* d_ws, size_t ws_size,
                              hipStream_t stream) {
  const float* x = (const float*)d_in[0];        // [16,8192,256]
  const int* mask = (const int*)d_in[1];         // [16,64,8192]
  const float* Wv = (const float*)d_in[2];
  const float* bv = (const float*)d_in[3];
  const float* Wk = (const float*)d_in[4];
  const float* bk = (const float*)d_in[5];
  const float* queries = (const float*)d_in[6];  // [64,256]

  char* ws = (char*)d_ws;
  u16* qf = (u16*)ws;                        // [0, 32768)  frag-ordered Q' bf16
  float* qb = (float*)(ws + 32768);          // [32768, 33792)
  float* pw = (float*)(ws + 33792);          // [33792, +1MB)  per-block wsum partials
  float* dpart = (float*)(ws + 33792 + 1048576);  // 1024 floats
  float* out = (float*)d_out;                // 16*256
  float* att = out + B_ * D_;                // 16*8192

  prep_qk<<<N_, D_, 0, stream>>>(queries, Wk, bk, qf, qb);
  attn_main<<<dim3(64, B_), 256, 0, stream>>>(x, mask, qf, qb, pw, dpart, att);
  finalize_k<<<dim3(B_, 33), 256, 0, stream>>>(pw, dpart, Wv, bv, out, att);
}

// Round 4
// 247.568 us; speedup vs baseline: 1.4088x; 1.3054x over previous
//
#include <hip/hip_runtime.h>

// B=16, S=8192, D=256, N=64, IDX=3, slot-norm softmax.
// logits = (x·Q' + qb)/16 with Q' = queries@Wk;  out = (wsum·Wv^T)/denom + bv
// wsum[b,:] = sum_s p3[b,s]·x[b,s,:], denom[b] = sum_s p3[b,s].
// v4: barrier-free main loop. Q' + mask bits staged once (1 barrier). Each wave
// owns a private 16-row x slab in LDS (same-wave ds ordering, no syncthreads).
// Register prefetch of next iter's x rows overlaps HBM latency with compute.
// Both MFMA operands from LDS (v2/v3 showed global frags die on L2 thrash).

#define B_ 16
#define S_ 8192
#define D_ 256
#define N_ 64
#define NEG_ (-9e15f)
#define LSTR 264  // slab row stride in bf16 elems (16B-aligned, bank-even)

typedef __attribute__((ext_vector_type(8))) short s8_t;   // 8 bf16 MFMA frag
typedef __attribute__((ext_vector_type(4))) float f4_t;   // 4 fp32 MFMA acc
typedef unsigned int u32;
typedef unsigned short u16;

__device__ __forceinline__ u16 f2bf(float f) {
  u32 u = __builtin_bit_cast(u32, f);
  u += 0x7fffu + ((u >> 16) & 1u);   // RNE
  return (u16)(u >> 16);
}
__device__ __forceinline__ float bflo(u32 p) { return __builtin_bit_cast(float, p << 16); }
__device__ __forceinline__ float bfhi(u32 p) { return __builtin_bit_cast(float, p & 0xffff0000u); }

// ---- prep: Q' = queries@Wk -> bf16 FRAG-ORDERED for MFMA B-operand; qb[n]=q·bk ----
__global__ void prep_qk(const float* __restrict__ queries, const float* __restrict__ Wk,
                        const float* __restrict__ bk, u16* __restrict__ qf,
                        float* __restrict__ qb) {
  __shared__ float ql[D_];
  __shared__ float rb[D_];
  const int n = blockIdx.x, d = threadIdx.x;
  const float qv = queries[n * D_ + d];
  ql[d] = qv;
  rb[d] = qv * bk[d];
  __syncthreads();
  float a0 = 0.f, a1 = 0.f, a2 = 0.f, a3 = 0.f;
#pragma unroll 4
  for (int e = 0; e < D_; e += 4) {
    a0 = fmaf(ql[e + 0], Wk[(e + 0) * D_ + d], a0);
    a1 = fmaf(ql[e + 1], Wk[(e + 1) * D_ + d], a1);
    a2 = fmaf(ql[e + 2], Wk[(e + 2) * D_ + d], a2);
    a3 = fmaf(ql[e + 3], Wk[(e + 3) * D_ + d], a3);
  }
  const float acc = (a0 + a1) + (a2 + a3);
  // frag elem j of frag (t4,c,lane=g*16+c15) = Q'[16t4+c15][32c+8g+j]
  const int t4 = n >> 4, c15 = n & 15, c = d >> 5, g = (d >> 3) & 3, j = d & 7;
  qf[((t4 * 8 + c) * 64 + g * 16 + c15) * 8 + j] = f2bf(acc);
  for (int s = 128; s > 0; s >>= 1) { __syncthreads(); if (d < s) rb[d] += rb[d + s]; }
  if (d == 0) qb[n] = rb[0];
}

// ---- main: 512 blocks (2/CU), 256 s per block, 1 prologue barrier ----
__global__ __launch_bounds__(256, 2) void attn_main(
    const float* __restrict__ x, const int* __restrict__ mask,
    const u16* __restrict__ qf, const float* __restrict__ qb,
    float* __restrict__ pw, float* __restrict__ dpart, float* __restrict__ att) {
  __shared__ __align__(16) u16 q_lds[16384];        // 32KB Q' frag-ordered
  __shared__ __align__(16) u16 slab[4][16 * LSTR];  // 33KB wave-private x slabs
  __shared__ u32 pmL[4 * 256];                      // 4KB mask bits [np][sl]

  const int t = threadIdx.x;
  const int lane = t & 63;
  const int w = t >> 6;
  const int c15 = lane & 15;
  const int g = lane >> 4;
  const int b = blockIdx.y;
  const int sb = blockIdx.x;
  const int s0 = sb * 256;

  // stage Q' (linear copy, frag order already matches readers)
#pragma unroll
  for (int i = 0; i < 8; ++i)
    ((uint4*)q_lds)[t + 256 * i] = ((const uint4*)qf)[t + 256 * i];

  // stage mask bits for all 256 s (coalesced 256B per wave-instr)
  {
    const int np = t >> 6, s = t & 63;
#pragma unroll
    for (int q = 0; q < 4; ++q) {
      const int* mrow = mask + ((long)b * N_ + np * 16) * S_ + s0 + q * 64 + s;
      u32 bits = 0;
#pragma unroll
      for (int i = 0; i < 16; ++i) bits |= (u32)(mrow[i * S_] != 0) << i;
      pmL[np * 256 + q * 64 + s] = bits;
    }
  }

  const float qbv0 = qb[c15], qbv1 = qb[16 + c15], qbv2 = qb[32 + c15], qbv3 = qb[48 + c15];
  u16* myslab = slab[w];
  const float4* x4 = (const float4*)x;
  const long xbase = ((long)b * S_ + s0 + 16 * w) * 64 + lane;  // float4 units

  f4_t wacc = {0.f, 0.f, 0.f, 0.f};  // lane owns cols lane*4..+3
  float dacc = 0.f;

  // prefetch iter 0 rows into regs
  float4 pf[16];
#pragma unroll
  for (int r = 0; r < 16; ++r) pf[r] = x4[xbase + (long)r * 64];

  __syncthreads();  // q_lds + pmL ready (slabs are wave-private, never synced)

#pragma unroll
  for (int i = 0; i < 4; ++i) {
    // commit prefetched rows to this wave's slab (bank-even b64 writes)
#pragma unroll
    for (int r = 0; r < 16; ++r) {
      uint2 h;
      h.x = (u32)f2bf(pf[r].x) | ((u32)f2bf(pf[r].y) << 16);
      h.y = (u32)f2bf(pf[r].z) | ((u32)f2bf(pf[r].w) << 16);
      *(uint2*)&myslab[r * LSTR + lane * 4] = h;
    }
    // prefetch next iter (overlaps with compute below)
    if (i < 3) {
#pragma unroll
      for (int r = 0; r < 16; ++r) pf[r] = x4[xbase + ((i + 1) * 64 + (long)r) * 64];
    }

    // logits: A from own slab, B from q_lds (all ds_read_b128, 2-way max = free)
    const u16* arow = &myslab[c15 * LSTR + g * 8];
    f4_t acc0 = {0.f,0.f,0.f,0.f}, acc1 = {0.f,0.f,0.f,0.f};
    f4_t acc2 = {0.f,0.f,0.f,0.f}, acc3 = {0.f,0.f,0.f,0.f};
#pragma unroll
    for (int c = 0; c < 8; ++c) {
      const s8_t a  = *(const s8_t*)&arow[c * 32];
      acc0 = __builtin_amdgcn_mfma_f32_16x16x32_bf16(a, *(const s8_t*)&q_lds[((0 * 8 + c) * 64 + lane) * 8], acc0, 0, 0, 0);
      acc1 = __builtin_amdgcn_mfma_f32_16x16x32_bf16(a, *(const s8_t*)&q_lds[((1 * 8 + c) * 64 + lane) * 8], acc1, 0, 0, 0);
      acc2 = __builtin_amdgcn_mfma_f32_16x16x32_bf16(a, *(const s8_t*)&q_lds[((2 * 8 + c) * 64 + lane) * 8], acc2, 0, 0, 0);
      acc3 = __builtin_amdgcn_mfma_f32_16x16x32_bf16(a, *(const s8_t*)&q_lds[((3 * 8 + c) * 64 + lane) * 8], acc3, 0, 0, 0);
    }

    // softmax over n=64; C-layout col=c15, row=g*4+r
    float unorm[4];
#pragma unroll
    for (int r = 0; r < 4; ++r) {
      const int sl = i * 64 + 16 * w + g * 4 + r;
      const u32 m0 = pmL[0 * 256 + sl], m1 = pmL[1 * 256 + sl];
      const u32 m2 = pmL[2 * 256 + sl], m3 = pmL[3 * 256 + sl];
      const float lf0 = ((m0 >> c15) & 1) ? (acc0[r] + qbv0) * 0.0625f : NEG_;
      const float lf1 = ((m1 >> c15) & 1) ? (acc1[r] + qbv1) * 0.0625f : NEG_;
      const float lf2 = ((m2 >> c15) & 1) ? (acc2[r] + qbv2) * 0.0625f : NEG_;
      const float lf3 = ((m3 >> c15) & 1) ? (acc3[r] + qbv3) * 0.0625f : NEG_;
      float m = fmaxf(fmaxf(lf0, lf1), fmaxf(lf2, lf3));
      m = fmaxf(m, __shfl_xor(m, 1));
      m = fmaxf(m, __shfl_xor(m, 2));
      m = fmaxf(m, __shfl_xor(m, 4));
      m = fmaxf(m, __shfl_xor(m, 8));
      const float e0 = __expf(lf0 - m);
      float sm = e0 + __expf(lf1 - m) + __expf(lf2 - m) + __expf(lf3 - m);
      sm += __shfl_xor(sm, 1);
      sm += __shfl_xor(sm, 2);
      sm += __shfl_xor(sm, 4);
      sm += __shfl_xor(sm, 8);
      const float e3 = __shfl(e0, (lane & 48) | 3);  // n=IDX=3: t4=0, c15==3
      unorm[r] = e3 / sm;
    }
    if (c15 == 3) {
      f4_t u = {unorm[0], unorm[1], unorm[2], unorm[3]};
      *(f4_t*)&att[(long)b * S_ + s0 + i * 64 + 16 * w + g * 4] = u;
    }

    // wsum over this wave's 16 rows; lane owns cols lane*4..+3
#pragma unroll
    for (int r = 0; r < 4; ++r) {
#pragma unroll
      for (int gg = 0; gg < 4; ++gg) {
        const float a_s = __shfl(unorm[r], gg * 16);  // local row gg*4+r
        const uint2 h = *(const uint2*)&myslab[(gg * 4 + r) * LSTR + lane * 4];
        wacc[0] = fmaf(a_s, bflo(h.x), wacc[0]);
        wacc[1] = fmaf(a_s, bfhi(h.x), wacc[1]);
        wacc[2] = fmaf(a_s, bflo(h.y), wacc[2]);
        wacc[3] = fmaf(a_s, bfhi(h.y), wacc[3]);
        dacc += a_s;  // lane-uniform
      }
    }
  }

  // block combine (slabs dead -> overlay), single end barrier pair
  __syncthreads();
  float* ldsW = (float*)slab;  // 257 floats
  if (t < 256) ldsW[t] = 0.f;
  if (t == 0) ldsW[256] = 0.f;
  __syncthreads();
#pragma unroll
  for (int j = 0; j < 4; ++j) atomicAdd(&ldsW[lane * 4 + j], wacc[j]);
  if (lane == 0) atomicAdd(&ldsW[256], dacc);
  __syncthreads();
  const int blk = b * 32 + sb;
  pw[(long)blk * D_ + t] = ldsW[t];
  if (t == 0) dpart[blk] = ldsW[256];
}

// ---- finalize: part 0 => reduce wsum + GEMV; parts 1..32 => att renorm ----
__global__ void finalize_k(const float* __restrict__ pw, const float* __restrict__ dpart,
                           const float* __restrict__ Wv, const float* __restrict__ bv,
                           float* __restrict__ out, float* __restrict__ att) {
  __shared__ float red[32];
  __shared__ float wl[D_];
  const int b = blockIdx.x, t = threadIdx.x, part = blockIdx.y;
  if (t < 32) red[t] = dpart[b * 32 + t];
  __syncthreads();
  if (t < 16) red[t] += red[t + 16];
  __syncthreads();
  if (t < 8) red[t] += red[t + 8];
  __syncthreads();
  if (t < 4) red[t] += red[t + 4];
  __syncthreads();
  if (t < 2) red[t] += red[t + 2];
  __syncthreads();
  if (t == 0) red[0] += red[1];
  __syncthreads();
  const float dn = red[0];
  if (part == 0) {
    float s0 = 0.f, s1 = 0.f, s2 = 0.f, s3 = 0.f;
    const float* p = pw + (long)b * 32 * D_ + t;
#pragma unroll 4
    for (int sb = 0; sb < 32; sb += 4) {  // coalesced 1KB per iter
      s0 += p[(sb + 0) * D_]; s1 += p[(sb + 1) * D_];
      s2 += p[(sb + 2) * D_]; s3 += p[(sb + 3) * D_];
    }
    wl[t] = (s0 + s1) + (s2 + s3);
    __syncthreads();
    const float4* wr = (const float4*)&Wv[t * D_];
    const float4* wv = (const float4*)wl;
    float d0 = 0.f, d1 = 0.f, d2 = 0.f, d3 = 0.f;
#pragma unroll 8
    for (int e = 0; e < 64; ++e) {
      const float4 a = wv[e], w4 = wr[e];
      d0 = fmaf(a.x, w4.x, d0); d1 = fmaf(a.y, w4.y, d1);
      d2 = fmaf(a.z, w4.z, d2); d3 = fmaf(a.w, w4.w, d3);
    }
    out[b * D_ + t] = ((d0 + d1) + (d2 + d3)) / dn + bv[t];
  } else {
    const float inv = 1.0f / dn;
    att[(long)b * S_ + (part - 1) * 256 + t] *= inv;
  }
}

extern "C" void kernel_launch(void* const* d_in, const int* in_sizes, int n_in,
                              void* d_out, int out_size, void* d_ws, size_t ws_size,
                              hipStream_t stream) {
  const float* x = (const float*)d_in[0];        // [16,8192,256]
  const int* mask = (const int*)d_in[1];         // [16,64,8192]
  const float* Wv = (const float*)d_in[2];
  const float* bv = (const float*)d_in[3];
  const float* Wk = (const float*)d_in[4];
  const float* bk = (const float*)d_in[5];
  const float* queries = (const float*)d_in[6];  // [64,256]

  char* ws = (char*)d_ws;
  u16* qf = (u16*)ws;                        // [0, 32768)  frag-ordered Q' bf16
  float* qb = (float*)(ws + 32768);          // [32768, 33792)
  float* pw = (float*)(ws + 33792);          // 512 x 256 f32 partials (512KB)
  float* dpart = (float*)(ws + 33792 + 524288);  // 512 floats
  float* out = (float*)d_out;                // 16*256
  float* att = out + B_ * D_;                // 16*8192

  prep_qk<<<N_, D_, 0, stream>>>(queries, Wk, bk, qf, qb);
  attn_main<<<dim3(32, B_), 256, 0, stream>>>(x, mask, qf, qb, pw, dpart, att);
  finalize_k<<<dim3(B_, 33), 256, 0, stream>>>(pw, dpart, Wv, bv, out, att);
}